// Round 11
// baseline (162.278 us; speedup 1.0000x reference)
//
#include <hip/hip_runtime.h>
#include <math.h>

// ---------------------------------------------------------------------------
// HDRL Poincare MLR, c=1.
//   arg = 2*(Bc*xa - Aq*pa) / (Bc*(1-x2)*an),  Aq = 1+x2-2px, Bc = 1-p2
//   out = copysign(asinh(|arg|), arg) * an      (Dd cancels exactly; Dd>0)
// px = <x_b, p_o>, xa = <x_b, a_o> via dual bf16 MFMA GEMM (shared x tiles).
//
// R10 "staircase": 8 waves 2Mx4N, BM=256 BN=128-dual, BK=32, 32 K-tiles.
//   * 3 LDS buffers (3 x 32 KB): stages for tile t+2 issued during tile t ->
//     boundary wait is counted vmcnt(4) with ~2 tiles of slack (never 0
//     until the forced t=30 drain).
//   * ONE barrier per tile (boundary only). Within a tile: two clusters,
//     each {stage 2 gloads | pinned read group | counted lgkm | 16 MFMA}.
//     lgkmcnt(4) leaves the af[4..7] group in flight under cluster-0 MFMAs;
//     sched_barrier(0) pins order (rule #18: MFMA hoists past asm lgkm).
//   * Paired-row LDS (row r | r+half in one 64-elem row) keeps the verified
//     conflict-free XOR chunk swizzle at BK=32 (R8-verified addressing).
//   Keeps: XCD column stripe (R4), fast epilogue (R4), setprio (T5).
// ---------------------------------------------------------------------------

#define B_DIM 8192
#define O_DIM 4096
#define K_DIM 1024

using f32x4  = __attribute__((ext_vector_type(4))) float;
using bf16x8 = __attribute__((ext_vector_type(8))) short;

__device__ inline unsigned short f2bf(float f) {
  union { float f; unsigned u; } v; v.f = f;
  unsigned u = v.u;
  u += 0x7FFFu + ((u >> 16) & 1u);   // RNE
  return (unsigned short)(u >> 16);
}

__device__ inline void load_lds16(const void* g, void* l) {
  __builtin_amdgcn_global_load_lds(
      (const __attribute__((address_space(1))) void*)g,
      (__attribute__((address_space(3))) void*)l, 16, 0, 0);
}

__device__ inline float frcp(float x)  { float r; asm("v_rcp_f32 %0, %1"  : "=v"(r) : "v"(x)); return r; }
__device__ inline float fsqrt_(float x){ float r; asm("v_sqrt_f32 %0, %1" : "=v"(r) : "v"(x)); return r; }
__device__ inline float flog2(float x) { float r; asm("v_log_f32 %0, %1"  : "=v"(r) : "v"(x)); return r; }

// ---- per-output-row stats + bf16 conversion (weight & projected bias) -----
__global__ __launch_bounds__(256) void prep_rows(
    const float* __restrict__ wgt, const float* __restrict__ bia,
    unsigned short* __restrict__ a_bf, unsigned short* __restrict__ p_bf,
    float* __restrict__ p2v, float* __restrict__ pav, float* __restrict__ anv)
{
  const int o = blockIdx.x, t = threadIdx.x;
  const float4 w = ((const float4*)(wgt + (size_t)o * K_DIM))[t];
  const float4 b = ((const float4*)(bia + (size_t)o * K_DIM))[t];
  float a2 = w.x*w.x + w.y*w.y + w.z*w.z + w.w*w.w;
  float b2 = b.x*b.x + b.y*b.y + b.z*b.z + b.w*b.w;
  float ab = w.x*b.x + w.y*b.y + w.z*b.z + w.w*b.w;
  #pragma unroll
  for (int off = 32; off; off >>= 1) {
    a2 += __shfl_down(a2, off);
    b2 += __shfl_down(b2, off);
    ab += __shfl_down(ab, off);
  }
  __shared__ float sa[4], sb[4], sc_[4];
  const int wv = t >> 6, ln = t & 63;
  if (ln == 0) { sa[wv] = a2; sb[wv] = b2; sc_[wv] = ab; }
  __syncthreads();
  const float A2 = sa[0] + sa[1] + sa[2] + sa[3];
  const float B2 = sb[0] + sb[1] + sb[2] + sb[3];
  const float AB = sc_[0] + sc_[1] + sc_[2] + sc_[3];
  const float norm = sqrtf(B2);
  const float maxn = 1.0f - 1e-5f;            // (1-PROJ_EPS)/sqrt(c), c=1
  const float s = (norm > maxn) ? (maxn / norm) : 1.0f;
  if (t == 0) { p2v[o] = B2 * s * s; pav[o] = AB * s; anv[o] = sqrtf(A2); }
  unsigned short* ao = a_bf + (size_t)o * K_DIM + t * 4;
  unsigned short* po = p_bf + (size_t)o * K_DIM + t * 4;
  ao[0] = f2bf(w.x); ao[1] = f2bf(w.y); ao[2] = f2bf(w.z); ao[3] = f2bf(w.w);
  po[0] = f2bf(b.x * s); po[1] = f2bf(b.y * s); po[2] = f2bf(b.z * s); po[3] = f2bf(b.w * s);
}

// ---- per-batch-row stats + bf16 conversion of x ---------------------------
__global__ __launch_bounds__(256) void prep_x(
    const float* __restrict__ x, unsigned short* __restrict__ x_bf,
    float* __restrict__ x2v)
{
  const int bi = blockIdx.x, t = threadIdx.x;
  const float4 v = ((const float4*)(x + (size_t)bi * K_DIM))[t];
  float s2 = v.x*v.x + v.y*v.y + v.z*v.z + v.w*v.w;
  #pragma unroll
  for (int off = 32; off; off >>= 1) s2 += __shfl_down(s2, off);
  __shared__ float sl[4];
  const int wv = t >> 6, ln = t & 63;
  if (ln == 0) sl[wv] = s2;
  __syncthreads();
  if (t == 0) x2v[bi] = sl[0] + sl[1] + sl[2] + sl[3];
  unsigned short* xo = x_bf + (size_t)bi * K_DIM + t * 4;
  xo[0] = f2bf(v.x); xo[1] = f2bf(v.y); xo[2] = f2bf(v.z); xo[3] = f2bf(v.w);
}

// ---- main dual-GEMM + fused epilogue ---------------------------------------
// LDS buffer (16384 elems = 32 KB): A-paired[128 rows][64] @0 (row r holds
// global rows r | r+128), P-paired[64][64] @8192 (r | r+64), W-paired @12288.
// 3 buffers rotate; buf(kt%3) is read while buf((kt+2)%3) is being staged.
// Wave (wm=wv>>2, wn=wv&3): 128 rows x 32 cols of BOTH P and W;
// acc = accp[8][2] + acca[8][2] f32x4 = 128 regs.
__global__ __launch_bounds__(512, 2) void hdrl_main(
    const unsigned short* __restrict__ Xb,
    const unsigned short* __restrict__ Pb,
    const unsigned short* __restrict__ Ab,
    const float* __restrict__ x2v, const float* __restrict__ p2v,
    const float* __restrict__ pav, const float* __restrict__ anv,
    float* __restrict__ out)
{
  extern __shared__ unsigned short lds[];

  const int bid   = blockIdx.x;
  const int xcd   = bid & 7;
  const int local = bid >> 3;                 // 0..127 per XCD
  const int nt    = xcd * 4 + (local & 3);    // 4 n-columns per XCD
  const int mt    = local >> 2;               // 0..31
  const int row0 = mt * 256, col0 = nt * 128;
  const int t    = threadIdx.x;
  const int wv   = t >> 6, lane = t & 63;
  const int wm   = wv >> 2, wn = wv & 3;      // 2M x 4N waves
  const int lrow = lane & 15, kg = lane >> 4;

  // ---- fragment-read offsets (paired-row + XOR chunk swizzle) -------------
  // A: global row g = wm*128 + i*16 + lrow -> LDS row (i*16+lrow),
  //    chunk = (wm*4 + kg) ^ (lrow&7)   [g&7 == lrow&7]
  const int chA = (((wm << 2) + kg) ^ (lrow & 7)) << 3;
  // B (P/W): g = wn*32 + j*16 + lrow -> LDS row ((wn*32+j*16)&63)+lrow,
  //    chunk = (((wn*32+j*16)>>6)*4 + kg) ^ (lrow&7)
  const int bb0 = wn * 32, bb1 = wn * 32 + 16;
  const int rB0 = (bb0 & 63), rB1 = (bb1 & 63);
  const int chB0 = ((((bb0 >> 6) << 2) + kg) ^ (lrow & 7)) << 3;
  const int chB1 = ((((bb1 >> 6) << 2) + kg) ^ (lrow & 7)) << 3;

  // ---- staging addressing (inverse swizzle + pairing in the source) -------
  // dest (linear): lds[buf + region + q*4096 + wv*512 + lane*8]
  //   -> LDS row R = q*64 + wv*8 + (lane>>3), physical chunk c = lane&7
  // logical chunk cl = c ^ (R&7); source row += (cl>>2)*pair; k = (cl&3)*8
  const int Rb   = wv * 8 + (lane >> 3);
  const int cl   = (lane & 7) ^ ((lane >> 3) & 7);
  const int srcK = (cl & 3) * 8;
  const unsigned short* gA = Xb + (size_t)(row0 + Rb + (cl >> 2) * 128) * K_DIM + srcK;
  const unsigned short* gP = Pb + (size_t)(col0 + Rb + (cl >> 2) * 64 ) * K_DIM + srcK;
  const unsigned short* gW = Ab + (size_t)(col0 + Rb + (cl >> 2) * 64 ) * K_DIM + srcK;

#define STG_A(buf, q, k0n) load_lds16(gA + (size_t)(q)*64*K_DIM + (k0n), (void*)&lds[(buf) + (q)*4096 + wv*512])
#define STG_P(buf, k0n)    load_lds16(gP + (k0n), (void*)&lds[(buf) +  8192 + wv*512])
#define STG_W(buf, k0n)    load_lds16(gW + (k0n), (void*)&lds[(buf) + 12288 + wv*512])

  f32x4 accp[8][2], acca[8][2];
  #pragma unroll
  for (int i = 0; i < 8; ++i)
    #pragma unroll
    for (int j = 0; j < 2; ++j) { accp[i][j] = (f32x4)0.0f; acca[i][j] = (f32x4)0.0f; }

  // prologue: stage tile 0 -> buf0, tile 1 -> buf1; wait t0 only (4 left fly)
  STG_A(0, 0, 0);  STG_A(0, 1, 0);  STG_P(0, 0);  STG_W(0, 0);
  STG_A(16384, 0, 32); STG_A(16384, 1, 32); STG_P(16384, 32); STG_W(16384, 32);
  asm volatile("s_waitcnt vmcnt(4)" ::: "memory");
  __builtin_amdgcn_s_barrier();
  __builtin_amdgcn_sched_barrier(0);

  for (int kt = 0; kt < 32; ++kt) {
    const int cb  = (kt % 3) * 16384;
    const int sb  = ((kt + 2) % 3) * 16384;
    const int k0n = (kt + 2) * 32;
    const bool st = (kt < 30);

    bf16x8 af[8], bp2[2], bw2[2];

    // ======== cluster 0: stage A(t+2); reads G0(8)+G1(4); MFMA i0-3 ========
    if (st) { STG_A(sb, 0, k0n); STG_A(sb, 1, k0n); }
    // G0: af[0..3] + bp + bw (8 reads)
    #pragma unroll
    for (int i = 0; i < 4; ++i)
      af[i] = *(const bf16x8*)&lds[cb + (i * 16 + lrow) * 64 + chA];
    bp2[0] = *(const bf16x8*)&lds[cb +  8192 + (rB0 + lrow) * 64 + chB0];
    bp2[1] = *(const bf16x8*)&lds[cb +  8192 + (rB1 + lrow) * 64 + chB1];
    bw2[0] = *(const bf16x8*)&lds[cb + 12288 + (rB0 + lrow) * 64 + chB0];
    bw2[1] = *(const bf16x8*)&lds[cb + 12288 + (rB1 + lrow) * 64 + chB1];
    __builtin_amdgcn_sched_barrier(0);          // pin: G0 issued before G1
    // G1: af[4..7] (4 reads) — left in flight under cluster-0 MFMAs
    #pragma unroll
    for (int i = 4; i < 8; ++i)
      af[i] = *(const bf16x8*)&lds[cb + (i * 16 + lrow) * 64 + chA];
    asm volatile("s_waitcnt lgkmcnt(4)" ::: "memory");   // G0 done, G1 flying
    __builtin_amdgcn_sched_barrier(0);          // rule #18: no MFMA hoist
    __builtin_amdgcn_s_setprio(1);
    #pragma unroll
    for (int i = 0; i < 4; ++i)
      #pragma unroll
      for (int j = 0; j < 2; ++j) {
        accp[i][j] = __builtin_amdgcn_mfma_f32_16x16x32_bf16(af[i], bp2[j], accp[i][j], 0, 0, 0);
        acca[i][j] = __builtin_amdgcn_mfma_f32_16x16x32_bf16(af[i], bw2[j], acca[i][j], 0, 0, 0);
      }
    __builtin_amdgcn_s_setprio(0);
    __builtin_amdgcn_sched_barrier(0);

    // ======== cluster 1: stage P,W(t+2); wait G1; MFMA i4-7 ================
    if (st) { STG_P(sb, k0n); STG_W(sb, k0n); }
    asm volatile("s_waitcnt lgkmcnt(0)" ::: "memory");   // G1 done
    __builtin_amdgcn_sched_barrier(0);
    __builtin_amdgcn_s_setprio(1);
    #pragma unroll
    for (int i = 4; i < 8; ++i)
      #pragma unroll
      for (int j = 0; j < 2; ++j) {
        accp[i][j] = __builtin_amdgcn_mfma_f32_16x16x32_bf16(af[i], bp2[j], accp[i][j], 0, 0, 0);
        acca[i][j] = __builtin_amdgcn_mfma_f32_16x16x32_bf16(af[i], bw2[j], acca[i][j], 0, 0, 0);
      }
    __builtin_amdgcn_s_setprio(0);

    // ======== boundary: counted vmcnt (never 0 until forced) + barrier =====
    if (kt < 31) {
      if (kt == 30) asm volatile("s_waitcnt vmcnt(0)" ::: "memory");
      else          asm volatile("s_waitcnt vmcnt(4)" ::: "memory");
      __builtin_amdgcn_s_barrier();
      __builtin_amdgcn_sched_barrier(0);
    }
  }

  // fused epilogue: C/D layout col = lane&15, row = (lane>>4)*4 + reg.
  // arg = 2*(Bc*xa - Aq*pa) / (Bc*(1-x2)*an); out = copysign(asinh|arg|,arg)*an
  float Bcj[2], paj[2], dja[2], lcj[2];
  #pragma unroll
  for (int j = 0; j < 2; ++j) {
    const int col = col0 + wn * 32 + j * 16 + lrow;
    const float Bc = 1.0f - p2v[col];
    const float an = anv[col];
    Bcj[j] = Bc; paj[j] = pav[col];
    dja[j] = Bc * an;                 // denom col factor
    lcj[j] = 0.69314718f * an;        // ln2 * a_norm
  }
  #pragma unroll
  for (int i = 0; i < 8; ++i) {
    const int rbase = row0 + wm * 128 + i * 16 + kg * 4;
    #pragma unroll
    for (int r = 0; r < 4; ++r) {
      const int row = rbase + r;
      const float x2 = x2v[row];
      const float Aqh = 1.0f + x2;
      const float omx = 1.0f - x2;
      float* orow = out + (size_t)row * O_DIM + col0 + wn * 32 + lrow;
      #pragma unroll
      for (int j = 0; j < 2; ++j) {
        const float px = accp[i][j][r];
        const float xa = acca[i][j][r];
        const float numer = Bcj[j] * xa - (Aqh - 2.0f * px) * paj[j];
        const float denom = dja[j] * omx + 1e-15f;
        const float arg = 2.0f * numer * frcp(denom);
        const float aa  = fabsf(arg);
        const float u   = aa + fsqrt_(__builtin_fmaf(aa, aa, 1.0f));
        orow[j * 16] = copysignf(flog2(u) * lcj[j], arg);
      }
    }
  }
#undef STG_A
#undef STG_P
#undef STG_W
}

extern "C" void kernel_launch(void* const* d_in, const int* in_sizes, int n_in,
                              void* d_out, int out_size, void* d_ws, size_t ws_size,
                              hipStream_t stream) {
  (void)in_sizes; (void)n_in; (void)out_size; (void)ws_size;
  const float* x = (const float*)d_in[0];
  const float* w = (const float*)d_in[1];
  const float* b = (const float*)d_in[2];
  float* out = (float*)d_out;

  char* ws = (char*)d_ws;
  unsigned short* x_bf = (unsigned short*)ws;                               // 16 MB
  unsigned short* p_bf = (unsigned short*)(ws + (size_t)16 * 1024 * 1024);  //  8 MB
  unsigned short* a_bf = (unsigned short*)(ws + (size_t)24 * 1024 * 1024);  //  8 MB
  float* p2v = (float*)(ws + (size_t)32 * 1024 * 1024);
  float* pav = p2v + O_DIM;
  float* anv = pav + O_DIM;
  float* x2v = anv + O_DIM;

  prep_rows<<<O_DIM, 256, 0, stream>>>(w, b, a_bf, p_bf, p2v, pav, anv);
  prep_x<<<B_DIM, 256, 0, stream>>>(x, x_bf, x2v);

  hipFuncSetAttribute((const void*)hdrl_main,
                      hipFuncAttributeMaxDynamicSharedMemorySize, 98304);
  const int grid = (B_DIM / 256) * (O_DIM / 128);   // 1024
  hdrl_main<<<grid, 512, 98304, stream>>>(x_bf, p_bf, a_bf, x2v, p2v, pav, anv, out);
}

// Round 12
// 150.318 us; speedup vs baseline: 1.0796x; 1.0796x over previous
//
#include <hip/hip_runtime.h>
#include <math.h>

// ---------------------------------------------------------------------------
// HDRL Poincare MLR, c=1.
//   arg = 2*(Bc*xa - Aq*pa) / (Bc*(1-x2)*an),  Aq = 1+x2-2px, Bc = 1-p2
//   out = copysign(asinh(|arg|), arg) * an      (Dd cancels exactly; Dd>0)
// px = <x_b, p_o>, xa = <x_b, a_o> via dual bf16 MFMA GEMM (shared x tiles).
//
// R11: faithful m201 8-phase port. 8 waves 2Mx4N, BM=256, dual BN=128,
//   BK=64, 2 K-tiles/iteration, 8 phases each {<=12 ds_read | 2 gload stage
//   -> BAR -> lgkm0 -> setprio -> 16 MFMA -> setprio -> BAR}.
//   Stage-into-freed-region (P after ph1, W after ph2, A after ph3);
//   each half-tile staged ~7 phases before first read. vmcnt(6) at ph4/ph8
//   ONLY (counted, never 0 until the final iteration). LDS 128 KB:
//   2 buf x {Ah0,Ah1,P,W} x 128x64 bf16. Quadrants/K-tile:
//   [i0-3 P | i0-3 W | i4-7 P | i4-7 W] -> reads 12/4/8/0 per phase.
//   Keeps: XCD stripe (R4), XOR swizzle (R2/R5-verified), fast epilogue (R4).
// ---------------------------------------------------------------------------

#define B_DIM 8192
#define O_DIM 4096
#define K_DIM 1024

using f32x4  = __attribute__((ext_vector_type(4))) float;
using bf16x8 = __attribute__((ext_vector_type(8))) short;

__device__ inline unsigned short f2bf(float f) {
  union { float f; unsigned u; } v; v.f = f;
  unsigned u = v.u;
  u += 0x7FFFu + ((u >> 16) & 1u);   // RNE
  return (unsigned short)(u >> 16);
}

__device__ inline void load_lds16(const void* g, void* l) {
  __builtin_amdgcn_global_load_lds(
      (const __attribute__((address_space(1))) void*)g,
      (__attribute__((address_space(3))) void*)l, 16, 0, 0);
}

__device__ inline float frcp(float x)  { float r; asm("v_rcp_f32 %0, %1"  : "=v"(r) : "v"(x)); return r; }
__device__ inline float fsqrt_(float x){ float r; asm("v_sqrt_f32 %0, %1" : "=v"(r) : "v"(x)); return r; }
__device__ inline float flog2(float x) { float r; asm("v_log_f32 %0, %1"  : "=v"(r) : "v"(x)); return r; }

// ---- per-output-row stats + bf16 conversion (weight & projected bias) -----
__global__ __launch_bounds__(256) void prep_rows(
    const float* __restrict__ wgt, const float* __restrict__ bia,
    unsigned short* __restrict__ a_bf, unsigned short* __restrict__ p_bf,
    float* __restrict__ p2v, float* __restrict__ pav, float* __restrict__ anv)
{
  const int o = blockIdx.x, t = threadIdx.x;
  const float4 w = ((const float4*)(wgt + (size_t)o * K_DIM))[t];
  const float4 b = ((const float4*)(bia + (size_t)o * K_DIM))[t];
  float a2 = w.x*w.x + w.y*w.y + w.z*w.z + w.w*w.w;
  float b2 = b.x*b.x + b.y*b.y + b.z*b.z + b.w*b.w;
  float ab = w.x*b.x + w.y*b.y + w.z*b.z + w.w*b.w;
  #pragma unroll
  for (int off = 32; off; off >>= 1) {
    a2 += __shfl_down(a2, off);
    b2 += __shfl_down(b2, off);
    ab += __shfl_down(ab, off);
  }
  __shared__ float sa[4], sb[4], sc_[4];
  const int wv = t >> 6, ln = t & 63;
  if (ln == 0) { sa[wv] = a2; sb[wv] = b2; sc_[wv] = ab; }
  __syncthreads();
  const float A2 = sa[0] + sa[1] + sa[2] + sa[3];
  const float B2 = sb[0] + sb[1] + sb[2] + sb[3];
  const float AB = sc_[0] + sc_[1] + sc_[2] + sc_[3];
  const float norm = sqrtf(B2);
  const float maxn = 1.0f - 1e-5f;            // (1-PROJ_EPS)/sqrt(c), c=1
  const float s = (norm > maxn) ? (maxn / norm) : 1.0f;
  if (t == 0) { p2v[o] = B2 * s * s; pav[o] = AB * s; anv[o] = sqrtf(A2); }
  unsigned short* ao = a_bf + (size_t)o * K_DIM + t * 4;
  unsigned short* po = p_bf + (size_t)o * K_DIM + t * 4;
  ao[0] = f2bf(w.x); ao[1] = f2bf(w.y); ao[2] = f2bf(w.z); ao[3] = f2bf(w.w);
  po[0] = f2bf(b.x * s); po[1] = f2bf(b.y * s); po[2] = f2bf(b.z * s); po[3] = f2bf(b.w * s);
}

// ---- per-batch-row stats + bf16 conversion of x ---------------------------
__global__ __launch_bounds__(256) void prep_x(
    const float* __restrict__ x, unsigned short* __restrict__ x_bf,
    float* __restrict__ x2v)
{
  const int bi = blockIdx.x, t = threadIdx.x;
  const float4 v = ((const float4*)(x + (size_t)bi * K_DIM))[t];
  float s2 = v.x*v.x + v.y*v.y + v.z*v.z + v.w*v.w;
  #pragma unroll
  for (int off = 32; off; off >>= 1) s2 += __shfl_down(s2, off);
  __shared__ float sl[4];
  const int wv = t >> 6, ln = t & 63;
  if (ln == 0) sl[wv] = s2;
  __syncthreads();
  if (t == 0) x2v[bi] = sl[0] + sl[1] + sl[2] + sl[3];
  unsigned short* xo = x_bf + (size_t)bi * K_DIM + t * 4;
  xo[0] = f2bf(v.x); xo[1] = f2bf(v.y); xo[2] = f2bf(v.z); xo[3] = f2bf(v.w);
}

// ---- main dual-GEMM + fused epilogue ---------------------------------------
// LDS (bf16 elems): buffer 0 @0 (even K-tiles), buffer 1 @32768 (odd).
// Regions per buffer: Ah0 @+0 (rows 0-127), Ah1 @+8192 (rows 128-255),
// P @+16384, W @+24576 — each [128 rows][64 cols], XOR-chunk-swizzled.
// Wave (wm = wv>>2, wn = wv&3): rows wm*128..+128, cols wn*32..+32 of both.
__global__ __launch_bounds__(512, 2) void hdrl_main(
    const unsigned short* __restrict__ Xb,
    const unsigned short* __restrict__ Pb,
    const unsigned short* __restrict__ Ab,
    const float* __restrict__ x2v, const float* __restrict__ p2v,
    const float* __restrict__ pav, const float* __restrict__ anv,
    float* __restrict__ out)
{
  extern __shared__ unsigned short lds[];

  const int bid   = blockIdx.x;
  const int xcd   = bid & 7;
  const int local = bid >> 3;                 // 0..127 per XCD
  const int nt    = xcd * 4 + (local & 3);    // 4 n-columns per XCD
  const int mt    = local >> 2;               // 0..31
  const int row0 = mt * 256, col0 = nt * 128;
  const int t    = threadIdx.x;
  const int wv   = t >> 6, lane = t & 63;
  const int wm   = wv >> 2, wn = wv & 3;      // 2M x 4N waves
  const int lrow = lane & 15, kg = lane >> 4;
  const int sw   = (lrow & 7) << 3;           // read-side XOR key (elems)
  const int kbs0 = (kg * 8) ^ sw;
  const int kbs1 = (32 + kg * 8) ^ sw;
  const int aoff = wm * 8192;                 // A region for this wave
  const int boff = (wn * 32 + lrow) * 64;     // B row base (within region)

  // staging sources (R5-verified): thread t covers row sr, swizzled col
  const int sr   = t >> 3;                    // 0..63
  const int scol = ((t & 7) ^ (sr & 7)) * 8;
  const unsigned short* gA = Xb + (size_t)(row0 + sr) * K_DIM + scol;
  const unsigned short* gP = Pb + (size_t)(col0 + sr) * K_DIM + scol;
  const unsigned short* gW = Ab + (size_t)(col0 + sr) * K_DIM + scol;

  f32x4 accp[8][2], acca[8][2];
  #pragma unroll
  for (int i = 0; i < 8; ++i)
    #pragma unroll
    for (int j = 0; j < 2; ++j) { accp[i][j] = (f32x4)0.0f; acca[i][j] = (f32x4)0.0f; }

#define STG(dst, src, roff, kel) \
  load_lds16((src) + (size_t)(roff) * K_DIM + (kel), (void*)&lds[(dst) + wv * 512])
#define BAR()   __builtin_amdgcn_s_barrier()
#define LGKM0() do { asm volatile("s_waitcnt lgkmcnt(0)" ::: "memory"); \
                     __builtin_amdgcn_sched_barrier(0); } while (0)
#define RD_AF(cb, ib)                                                          \
  _Pragma("unroll") for (int i = 0; i < 4; ++i) {                              \
    af[i][0] = *(const bf16x8*)&lds[(cb) + aoff + (((ib)+i)*16 + lrow)*64 + kbs0]; \
    af[i][1] = *(const bf16x8*)&lds[(cb) + aoff + (((ib)+i)*16 + lrow)*64 + kbs1]; \
  }
#define RD_B(B, cb, rg)                                                        \
  _Pragma("unroll") for (int j = 0; j < 2; ++j) {                              \
    B[j][0] = *(const bf16x8*)&lds[(cb) + (rg) + boff + j*1024 + kbs0];        \
    B[j][1] = *(const bf16x8*)&lds[(cb) + (rg) + boff + j*1024 + kbs1];        \
  }
#define QMFMA(ACC, ib, B)                                                      \
  __builtin_amdgcn_s_setprio(1);                                               \
  _Pragma("unroll") for (int i = 0; i < 4; ++i)                                \
    _Pragma("unroll") for (int j = 0; j < 2; ++j) {                            \
      ACC[(ib)+i][j] = __builtin_amdgcn_mfma_f32_16x16x32_bf16(af[i][0], B[j][0], ACC[(ib)+i][j], 0, 0, 0); \
      ACC[(ib)+i][j] = __builtin_amdgcn_mfma_f32_16x16x32_bf16(af[i][1], B[j][1], ACC[(ib)+i][j], 0, 0, 0); \
    }                                                                          \
  __builtin_amdgcn_s_setprio(0)

  // prologue: tile 0 -> buf0, tile 1 -> buf1; vmcnt(8) guarantees tile 0
  STG(    0, gA,   0, 0); STG( 4096, gA,  64, 0);
  STG( 8192, gA, 128, 0); STG(12288, gA, 192, 0);
  STG(16384, gP,   0, 0); STG(20480, gP,  64, 0);
  STG(24576, gW,   0, 0); STG(28672, gW,  64, 0);
  STG(32768+    0, gA,   0, 64); STG(32768+ 4096, gA,  64, 64);
  STG(32768+ 8192, gA, 128, 64); STG(32768+12288, gA, 192, 64);
  STG(32768+16384, gP,   0, 64); STG(32768+20480, gP,  64, 64);
  STG(32768+24576, gW,   0, 64); STG(32768+28672, gW,  64, 64);
  asm volatile("s_waitcnt vmcnt(8)" ::: "memory");
  BAR();
  __builtin_amdgcn_sched_barrier(0);

  for (int it = 0; it < 8; ++it) {
    const bool st = (it < 7);
    const int kA = (2 * it + 2) * 64;   // k-offset of tile t+2 (-> buf0)
    const int kB = (2 * it + 3) * 64;   // k-offset of tile t+3 (-> buf1)

    bf16x8 af[4][2], bp[2][2], bw[2][2];

    // =================== K-tile T = 2it  (buffer 0) ========================
    // ph1: read af[0..3] + bp (12); no stage; MFMA accp i0-3
    RD_AF(0, 0); RD_B(bp, 0, 16384);
    BAR(); LGKM0();
    QMFMA(accp, 0, bp);
    BAR();

    // ph2: read bw (4); stage P(t+2); MFMA acca i0-3
    RD_B(bw, 0, 24576);
    if (st) { STG(16384, gP, 0, kA); STG(20480, gP, 64, kA); }
    BAR(); LGKM0();
    QMFMA(acca, 0, bw);
    BAR();

    // ph3: read af[4..7] (8); stage W(t+2); MFMA accp i4-7
    RD_AF(0, 4);
    if (st) { STG(24576, gW, 0, kA); STG(28672, gW, 64, kA); }
    BAR(); LGKM0();
    QMFMA(accp, 4, bp);
    BAR();

    // ph4: no reads; stage Ah0(t+2); MFMA acca i4-7; vmcnt(6) [tile t+1 ok]
    if (st) { STG(0, gA, 0, kA); STG(4096, gA, 64, kA); }
    BAR(); LGKM0();
    QMFMA(acca, 4, bw);
    if (st) asm volatile("s_waitcnt vmcnt(6)" ::: "memory");
    else    asm volatile("s_waitcnt vmcnt(0)" ::: "memory");
    __builtin_amdgcn_sched_barrier(0);
    BAR();

    // =================== K-tile T+1 = 2it+1  (buffer 1) ====================
    // ph5: read af[0..3] + bp (12); stage Ah1(t+2); MFMA accp i0-3
    RD_AF(32768, 0); RD_B(bp, 32768, 16384);
    if (st) { STG(8192, gA, 128, kA); STG(12288, gA, 192, kA); }
    BAR(); LGKM0();
    QMFMA(accp, 0, bp);
    BAR();

    // ph6: read bw (4); stage P(t+3); MFMA acca i0-3
    RD_B(bw, 32768, 24576);
    if (st) { STG(32768+16384, gP, 0, kB); STG(32768+20480, gP, 64, kB); }
    BAR(); LGKM0();
    QMFMA(acca, 0, bw);
    BAR();

    // ph7: read af[4..7] (8); stage W(t+3); MFMA accp i4-7
    RD_AF(32768, 4);
    if (st) { STG(32768+24576, gW, 0, kB); STG(32768+28672, gW, 64, kB); }
    BAR(); LGKM0();
    QMFMA(accp, 4, bp);
    BAR();

    // ph8: no reads; stage Ah0+Ah1(t+3) (4); MFMA acca i4-7; vmcnt(6)
    if (st) { STG(32768+0, gA, 0, kB);   STG(32768+4096,  gA,  64, kB);
              STG(32768+8192, gA, 128, kB); STG(32768+12288, gA, 192, kB); }
    BAR(); LGKM0();
    QMFMA(acca, 4, bw);
    if (st) asm volatile("s_waitcnt vmcnt(6)" ::: "memory");
    __builtin_amdgcn_sched_barrier(0);
    BAR();
  }

  // fused epilogue: C/D layout col = lane&15, row = (lane>>4)*4 + reg.
  // arg = 2*(Bc*xa - Aq*pa) / (Bc*(1-x2)*an); out = copysign(asinh|arg|,arg)*an
  float Bcj[2], paj[2], dja[2], lcj[2];
  #pragma unroll
  for (int j = 0; j < 2; ++j) {
    const int col = col0 + wn * 32 + j * 16 + lrow;
    const float Bc = 1.0f - p2v[col];
    const float an = anv[col];
    Bcj[j] = Bc; paj[j] = pav[col];
    dja[j] = Bc * an;                 // denom col factor
    lcj[j] = 0.69314718f * an;        // ln2 * a_norm
  }
  #pragma unroll
  for (int i = 0; i < 8; ++i) {
    const int rbase = row0 + wm * 128 + i * 16 + kg * 4;
    #pragma unroll
    for (int r = 0; r < 4; ++r) {
      const int row = rbase + r;
      const float x2 = x2v[row];
      const float Aqh = 1.0f + x2;
      const float omx = 1.0f - x2;
      float* orow = out + (size_t)row * O_DIM + col0 + wn * 32 + lrow;
      #pragma unroll
      for (int j = 0; j < 2; ++j) {
        const float px = accp[i][j][r];
        const float xa = acca[i][j][r];
        const float numer = Bcj[j] * xa - (Aqh - 2.0f * px) * paj[j];
        const float denom = dja[j] * omx + 1e-15f;
        const float arg = 2.0f * numer * frcp(denom);
        const float aa  = fabsf(arg);
        const float u   = aa + fsqrt_(__builtin_fmaf(aa, aa, 1.0f));
        orow[j * 16] = copysignf(flog2(u) * lcj[j], arg);
      }
    }
  }
#undef STG
#undef BAR
#undef LGKM0
#undef RD_AF
#undef RD_B
#undef QMFMA
}

extern "C" void kernel_launch(void* const* d_in, const int* in_sizes, int n_in,
                              void* d_out, int out_size, void* d_ws, size_t ws_size,
                              hipStream_t stream) {
  (void)in_sizes; (void)n_in; (void)out_size; (void)ws_size;
  const float* x = (const float*)d_in[0];
  const float* w = (const float*)d_in[1];
  const float* b = (const float*)d_in[2];
  float* out = (float*)d_out;

  char* ws = (char*)d_ws;
  unsigned short* x_bf = (unsigned short*)ws;                               // 16 MB
  unsigned short* p_bf = (unsigned short*)(ws + (size_t)16 * 1024 * 1024);  //  8 MB
  unsigned short* a_bf = (unsigned short*)(ws + (size_t)24 * 1024 * 1024);  //  8 MB
  float* p2v = (float*)(ws + (size_t)32 * 1024 * 1024);
  float* pav = p2v + O_DIM;
  float* anv = pav + O_DIM;
  float* x2v = anv + O_DIM;

  prep_rows<<<O_DIM, 256, 0, stream>>>(w, b, a_bf, p_bf, p2v, pav, anv);
  prep_x<<<B_DIM, 256, 0, stream>>>(x, x_bf, x2v);

  hipFuncSetAttribute((const void*)hdrl_main,
                      hipFuncAttributeMaxDynamicSharedMemorySize, 131072);
  const int grid = (B_DIM / 256) * (O_DIM / 128);   // 1024
  hdrl_main<<<grid, 512, 131072, stream>>>(x_bf, p_bf, a_bf, x2v, p2v, pav, anv, out);
}